// Round 6
// baseline (198.063 us; speedup 1.0000x reference)
//
#include <hip/hip_runtime.h>

// mean(|box5(x)-box5(y)|) = mean(|box5(x-y)|); separable 5x5 box, pad=4.
// B=64, H=W=512, out 516x516.
// R6: MLP via async DMA. R2-R5 proved the register allocator always sinks
// VGPR-staged loads (VGPR 44/72/84/88), capping request BW at ~2.5 TB/s.
// global_load_lds keeps outstanding loads in the vmcnt queue (zero VGPR
// cost) -> allocator can't serialize them. Each wave owns a private 4-slot
// LDS ring (slot = x-row + y-row, 4 KB), 3-row lookahead = 12 outstanding
// 1KB DMAs/wave, consumed with raw s_waitcnt vmcnt(12/8/4/0). NO
// __syncthreads in the hot path -> no compiler vmcnt(0) drain.
// Persistent 512 blocks pull (img,band) work items off an atomic queue.

#define TRB            12
#define BANDS_PER_IMG  43                        // 43*12 = 516
#define TOTAL_BANDS    (BANDS_PER_IMG * 64)      // 2752
#define NROWS          (TRB + 4)                 // 16 input rows per band
#define NBLOCKS        512                       // persistent, 2/CU (LDS-capped)

typedef __attribute__((address_space(1))) const void glb_t;
typedef __attribute__((address_space(3))) void lds_t;

__global__ __launch_bounds__(256) void box_loss_kernel(
    const float* __restrict__ x, const float* __restrict__ y,
    float* __restrict__ ws, float* __restrict__ out)
{
    __shared__ float lds[4][4][1024];   // [wave][slot][x:0..511 | y:512..1023] = 64 KB
    __shared__ float wsum[4];

    const int lane = threadIdx.x & 63;
    const int w    = threadIdx.x >> 6;
    float* const wlds = &lds[w][0][0];

    unsigned* bandctr = (unsigned*)ws + 1;
    unsigned* donectr = (unsigned*)ws + 2;

    const int loff = lane * 4;          // DMA source: 16 B per lane

    float acc = 0.f;

    for (;;) {
        unsigned id;
        if (lane == 0) id = atomicAdd(bandctr, 1u);
        id = (unsigned)__shfl((int)id, 0, 64);
        if (id >= TOTAL_BANDS) break;

        const int img  = (int)(id / BANDS_PER_IMG);
        const int band = (int)(id - (unsigned)img * BANDS_PER_IMG);
        const int i0   = band * TRB;    // first output row of this band

        const float* xb = x + (size_t)img * (512 * 512);
        const float* yb = y + (size_t)img * (512 * 512);

        // issue input row (i0-4+k) into ring slot k&3: 4 x 1KB DMAs
        #define ISSUE_ROW(k) do {                                                        \
            const int rc_ = min(max(i0 - 4 + (k), 0), 511);                              \
            const float* gx_ = xb + (size_t)rc_ * 512 + loff;                            \
            const float* gy_ = yb + (size_t)rc_ * 512 + loff;                            \
            float* lb_ = wlds + ((k) & 3) * 1024;                                        \
            __builtin_amdgcn_global_load_lds((glb_t*)(gx_),       (lds_t*)(lb_),       16, 0, 0); \
            __builtin_amdgcn_global_load_lds((glb_t*)(gx_ + 256), (lds_t*)(lb_ + 256), 16, 0, 0); \
            __builtin_amdgcn_global_load_lds((glb_t*)(gy_),       (lds_t*)(lb_ + 512), 16, 0, 0); \
            __builtin_amdgcn_global_load_lds((glb_t*)(gy_ + 256), (lds_t*)(lb_ + 768), 16, 0, 0); \
        } while (0)

        ISSUE_ROW(0); ISSUE_ROW(1); ISSUE_ROW(2);

        float hist[5][8], v[8];
        #pragma unroll
        for (int j = 0; j < 8; ++j) v[j] = 0.f;
        #pragma unroll
        for (int s = 0; s < 5; ++s)
            #pragma unroll
            for (int j = 0; j < 8; ++j) hist[s][j] = 0.f;

        #pragma unroll
        for (int k = 0; k < NROWS; ++k) {
            if (k + 3 < NROWS) ISSUE_ROW(k + 3);

            // wait for row k's 4 DMAs; keep newer rows in flight
            if      (k < NROWS - 3)  asm volatile("s_waitcnt vmcnt(12)" ::: "memory");
            else if (k == NROWS - 3) asm volatile("s_waitcnt vmcnt(8)"  ::: "memory");
            else if (k == NROWS - 2) asm volatile("s_waitcnt vmcnt(4)"  ::: "memory");
            else                     asm volatile("s_waitcnt vmcnt(0)"  ::: "memory");

            const float* sl = wlds + (k & 3) * 1024;
            const float4 xa = *(const float4*)(sl + lane * 8);
            const float4 xc = *(const float4*)(sl + lane * 8 + 4);
            const float4 ya = *(const float4*)(sl + 512 + lane * 8);
            const float4 yc = *(const float4*)(sl + 512 + lane * 8 + 4);

            const int r = i0 - 4 + k;
            const bool valid = (r >= 0) & (r < 512);
            float d[8];
            d[0] = xa.x - ya.x; d[1] = xa.y - ya.y; d[2] = xa.z - ya.z; d[3] = xa.w - ya.w;
            d[4] = xc.x - yc.x; d[5] = xc.y - yc.y; d[6] = xc.z - yc.z; d[7] = xc.w - yc.w;
            #pragma unroll
            for (int j = 0; j < 8; ++j) d[j] = valid ? d[j] : 0.f;

            const int s5 = k % 5;            // compile-time under full unroll
            #pragma unroll
            for (int j = 0; j < 8; ++j) {
                v[j] += d[j] - hist[s5][j];
                hist[s5][j] = d[j];
            }

            if (k >= 4) {                    // output row i0 + (k-4)
                float h0 = __shfl_up(v[4], 1, 64);
                float h1 = __shfl_up(v[5], 1, 64);
                float h2 = __shfl_up(v[6], 1, 64);
                float h3 = __shfl_up(v[7], 1, 64);
                if (lane == 0) { h0 = 0.f; h1 = 0.f; h2 = 0.f; h3 = 0.f; }

                float s = h0 + h1 + h2 + h3 + v[0];   // out col c0
                acc += fabsf(s);
                s += v[1] - h0;   acc += fabsf(s);
                s += v[2] - h1;   acc += fabsf(s);
                s += v[3] - h2;   acc += fabsf(s);
                s += v[4] - h3;   acc += fabsf(s);
                s += v[5] - v[0]; acc += fabsf(s);
                s += v[6] - v[1]; acc += fabsf(s);
                s += v[7] - v[2]; acc += fabsf(s);
                if (lane == 63) {                     // out cols 512..515
                    float q = v[7];  acc += fabsf(q);
                    q += v[6];       acc += fabsf(q);
                    q += v[5];       acc += fabsf(q);
                    q += v[4];       acc += fabsf(q);
                }
            }
            // pin: next iteration's DMA issue must not hoist above these reads
            asm volatile("" ::: "memory");
        }
        #undef ISSUE_ROW
    }

    // ---- wave reduce, block reduce, global atomic, fused finalize
    #pragma unroll
    for (int off = 32; off > 0; off >>= 1)
        acc += __shfl_down(acc, off, 64);
    if (lane == 0) wsum[w] = acc;
    __syncthreads();

    if (threadIdx.x == 0) {
        float s = wsum[0] + wsum[1] + wsum[2] + wsum[3];
        atomicAdd(ws, s);
        __threadfence();
        unsigned done = atomicAdd(donectr, 1u);
        if (done == (unsigned)(NBLOCKS - 1)) {
            float total = atomicAdd(ws, 0.0f);   // coherent read of final sum
            out[0] = total * (1.0f / (25.0f * 64.0f * 516.0f * 516.0f));
        }
    }
}

extern "C" void kernel_launch(void* const* d_in, const int* in_sizes, int n_in,
                              void* d_out, int out_size, void* d_ws, size_t ws_size,
                              hipStream_t stream) {
    const float* x = (const float*)d_in[0];
    const float* y = (const float*)d_in[1];
    float* out = (float*)d_out;
    float* ws  = (float*)d_ws;

    hipMemsetAsync(ws, 0, 12, stream);  // ws[0]=sum, ws[1]=band ctr, ws[2]=done ctr

    box_loss_kernel<<<NBLOCKS, 256, 0, stream>>>(x, y, ws, out);
}